// Round 6
// baseline (981.608 us; speedup 1.0000x reference)
//
#include <hip/hip_runtime.h>

#define B 4
#define C 64
#define T 256
#define A 4096
#define RC 264        // residual columns = T + 8
#define PW 260        // fm position stride (257 real, 3 sentinel)
#define NITER 32
#define NBLK 256      // k_iter blocks
#define ATB 16        // atoms owned per k_iter block
#define WSTR 44       // wpad channel stride (floats): cg*12 mod 32 all-distinct
#define WROW 2816     // 64*WSTR

// ---------------- workspace layout (bytes) ----------------
#define WS_DN     0            // A*512 f32          = 8,388,608
#define WS_RES    8388608      // B*C*RC f32         =   270,336
#define WS_RECON  8658944      // B*C*RC f32         =   270,336
#define WS_FM     8929280      // B*A*PW f32         = 17,039,360
#define WS_PART   25968640     // parts[2][4][256] u64 = 16,384

typedef unsigned long long u64;

// pack: [monotone f32:32][~key:21][tag:11]; tag OR'd at store time
__device__ __forceinline__ u64 packmax21(float v, unsigned key) {
    unsigned u = __float_as_uint(v);
    u = (u & 0x80000000u) ? ~u : (u | 0x80000000u);
    return ((u64)u << 32) | ((u64)(0x1FFFFFu - key) << 11);
}

// ---------------- K1: unit-norm the dictionary ----------------
__global__ void k_norm(const float* __restrict__ d, float* __restrict__ dn) {
    const int atom = blockIdx.x * 4 + (threadIdx.x >> 6);
    const int lane = threadIdx.x & 63;
    const float* src = d + atom * 512;
    float4 v0 = ((const float4*)src)[lane * 2];
    float4 v1 = ((const float4*)src)[lane * 2 + 1];
    float s = v0.x*v0.x + v0.y*v0.y + v0.z*v0.z + v0.w*v0.w
            + v1.x*v1.x + v1.y*v1.y + v1.z*v1.z + v1.w*v1.w;
    #pragma unroll
    for (int off = 32; off; off >>= 1) s += __shfl_xor(s, off);
    const float denom = sqrtf(s) + 1e-8f;
    float* dst = dn + atom * 512;
    float4 o0 = make_float4(v0.x/denom, v0.y/denom, v0.z/denom, v0.w/denom);
    float4 o1 = make_float4(v1.x/denom, v1.y/denom, v1.z/denom, v1.w/denom);
    ((float4*)dst)[lane * 2]     = o0;
    ((float4*)dst)[lane * 2 + 1] = o1;
}

// ---------------- K2: init res/recon/fm-edge + zero parts ----------------
__global__ void k_init(const float* __restrict__ x, float* __restrict__ res,
                       float* __restrict__ recon, float* __restrict__ fm,
                       u64* __restrict__ parts) {
    if (blockIdx.x == 0)
        for (int i = threadIdx.x; i < 2048; i += blockDim.x) parts[i] = 0ull;
    const int tid = blockIdx.x * blockDim.x + threadIdx.x;
    const int nth = gridDim.x * blockDim.x;
    for (int i = tid; i < B * C * RC; i += nth) {
        const int col = i % RC;
        const int bc  = i / RC;
        res[i]   = (col < T) ? x[bc * T + col] : 0.0f;
        recon[i] = 0.0f;
    }
    for (int i = tid; i < B * A; i += nth) {
        float* row = fm + (long)i * PW;
        row[256] = 0.0f;
        row[257] = -1e30f; row[258] = -1e30f; row[259] = -1e30f;
    }
}

// ---------------- K3: full correlation fm[b][a][p], p=0..255 ----------------
__global__ __launch_bounds__(256) void k_conv(const float* __restrict__ res,
                                              const float* __restrict__ dn,
                                              float* __restrict__ fm) {
    __shared__ __align__(16) float lr[16 * 264];
    __shared__ __align__(16) float ld[32 * 16 * 8];
    const int b  = blockIdx.y;
    const int a0 = blockIdx.x * 32;
    const int t  = threadIdx.x;
    const int slot = t >> 5;
    const int pg   = t & 31;
    const int p0   = pg * 8;

    float acc[4][8] = {};

    for (int cb = 0; cb < 4; ++cb) {
        const float* rsrc = res + b * C * RC + cb * 16 * RC;
        for (int i = t; i < 16 * 264; i += 256) lr[i] = rsrc[i];
        const float* dsrc = dn + (long)a0 * 512 + cb * 128;
        for (int i = t; i < 4096; i += 256)
            ld[i] = dsrc[(long)(i >> 7) * 512 + (i & 127)];
        __syncthreads();

        for (int cc = 0; cc < 16; ++cc) {
            float rv[16];
            const float* r = lr + cc * 264 + p0;
            *(float4*)(rv)      = *(const float4*)(r);
            *(float4*)(rv + 4)  = *(const float4*)(r + 4);
            *(float4*)(rv + 8)  = *(const float4*)(r + 8);
            *(float4*)(rv + 12) = *(const float4*)(r + 12);
            float dk[32];
            #pragma unroll
            for (int ai = 0; ai < 4; ++ai) {
                const float* dp = ld + ((slot * 4 + ai) * 16 + cc) * 8;
                *(float4*)(dk + ai * 8)     = *(const float4*)(dp);
                *(float4*)(dk + ai * 8 + 4) = *(const float4*)(dp + 4);
            }
            #pragma unroll
            for (int ai = 0; ai < 4; ++ai)
                #pragma unroll
                for (int pi = 0; pi < 8; ++pi)
                    #pragma unroll
                    for (int kk = 0; kk < 8; ++kk)
                        acc[ai][pi] = fmaf(rv[pi + kk], dk[ai * 8 + kk], acc[ai][pi]);
        }
        __syncthreads();
    }

    #pragma unroll
    for (int ai = 0; ai < 4; ++ai) {
        float* outp = fm + ((long)b * A + a0 + slot * 4 + ai) * PW + p0;
        *(float4*)(outp)     = *(const float4*)&acc[ai][0];
        *(float4*)(outp + 4) = *(const float4*)&acc[ai][4];
    }
}

// ---------------- K4: fused loop — tagged-parts sync, reg-Gram, rowmax cache ----------------
__global__ __launch_bounds__(512) void k_iter(const float* __restrict__ dn,
                                              float* __restrict__ recon,
                                              float* __restrict__ fm,
                                              u64* __restrict__ parts) {
    __shared__ __align__(16) float wpad[4][WROW];   // winner rows, stride-44 channels
    __shared__ float g[ATB][4][17];                 // Gram values (padded)
    __shared__ u64 rmax[4][ATB];                    // per-row packed maxima (tagless)
    __shared__ int sflag[64];
    __shared__ int   watom[4], wpos[4];
    __shared__ float wval[4];

    const int bk = blockIdx.x;
    const int a0 = bk * ATB;
    const int t  = threadIdx.x;
    const int wv = t >> 6, ln = t & 63;
    const int a_ = t >> 5, tt = t & 31, bb_ = tt & 3, cg = tt >> 2;
    const int row = t >> 3, kk8 = t & 7;        // 64 rows x 8 threads
    const int r_ai = row & 15, r_b = row >> 4;
    float* frow = fm + ((long)r_b * A + a0 + r_ai) * PW;
    const unsigned rkey = (unsigned)((a0 + r_ai) * PW);

    // own atom channels in registers: channel c = j*8+cg of atom a0+a_
    float own[8][8];
    {
        const float* s = dn + (long)(a0 + a_) * 512 + cg * 8;
        #pragma unroll
        for (int j = 0; j < 8; ++j) {
            *(float4*)&own[j][0] = *(const float4*)(s + j * 64);
            *(float4*)&own[j][4] = *(const float4*)(s + j * 64 + 4);
        }
    }
    for (int i = t; i < 4 * WROW; i += 512) ((float*)wpad)[i] = 0.0f;

    // ---- initial full row scans -> rmax ----
    {
        u64 m = 0ull;
        #pragma unroll
        for (int i = 0; i <= 8; ++i) {
            const int idx4 = kk8 + i * 8;
            if (idx4 < 65) {
                const float4 v = ((const float4*)frow)[idx4];
                const unsigned e = rkey + idx4 * 4;
                u64 q0 = packmax21(v.x, e);
                u64 q1 = packmax21(v.y, e + 1);
                u64 q2 = packmax21(v.z, e + 2);
                u64 q3 = packmax21(v.w, e + 3);
                if (q1 > q0) q0 = q1;
                if (q3 > q2) q2 = q3;
                if (q2 > q0) q0 = q2;
                if (q0 > m)  m = q0;
            }
        }
        #pragma unroll
        for (int off = 1; off <= 4; off <<= 1) {
            u64 o = __shfl_xor(m, off);
            if (o > m) m = o;
        }
        if (kk8 == 0) rmax[r_b][r_ai] = m;
    }
    __syncthreads();

#define WINNER_STORE(pbuf, tagv)                                                    \
    if (wv == 0) {                                                                  \
        const int b_ = ln >> 4, ai_ = ln & 15;                                      \
        u64 m = rmax[b_][ai_];                                                      \
        _Pragma("unroll")                                                           \
        for (int off = 1; off <= 8; off <<= 1) {                                    \
            u64 o = __shfl_xor(m, off);                                             \
            if (o > m) m = o;                                                       \
        }                                                                           \
        if (ai_ == 0)                                                               \
            __hip_atomic_store(&parts[(pbuf) * 1024 + b_ * 256 + bk],               \
                               m | (u64)(tagv), __ATOMIC_RELAXED,                   \
                               __HIP_MEMORY_SCOPE_AGENT);                           \
    }

    WINNER_STORE(0, 1);

    for (int it = 0; it < NITER; ++it) {
        const int pbuf = it & 1;
        const unsigned tagv = (unsigned)(it + 1);

        // ---- wave 0: poll tagged parts, reduce winners ----
        if (wv == 0) {
            const u64* pb = parts + pbuf * 1024;
            u64 v[16];
            for (;;) {
                bool ok = true;
                #pragma unroll
                for (int b = 0; b < 4; ++b)
                    #pragma unroll
                    for (int j = 0; j < 4; ++j) {
                        v[b * 4 + j] = __hip_atomic_load(&pb[b * 256 + ln * 4 + j],
                                                         __ATOMIC_RELAXED, __HIP_MEMORY_SCOPE_AGENT);
                        ok &= ((unsigned)(v[b * 4 + j] & 0x7FFull) == tagv);
                    }
                if (__all(ok)) break;
                __builtin_amdgcn_s_sleep(1);
            }
            u64 w[4];
            #pragma unroll
            for (int b = 0; b < 4; ++b) {
                u64 m0 = v[b * 4], m1 = v[b * 4 + 1], m2 = v[b * 4 + 2], m3 = v[b * 4 + 3];
                if (m1 > m0) m0 = m1;
                if (m3 > m2) m2 = m3;
                if (m2 > m0) m0 = m2;
                w[b] = m0;
            }
            #pragma unroll
            for (int off = 1; off <= 32; off <<= 1) {
                #pragma unroll
                for (int b = 0; b < 4; ++b) {
                    u64 o = __shfl_xor(w[b], off);
                    if (o > w[b]) w[b] = o;
                }
            }
            if (ln < 4) {
                const u64 m = w[ln];
                const unsigned key = 0x1FFFFFu - (unsigned)((m >> 11) & 0x1FFFFFu);
                unsigned uv = (unsigned)(m >> 32);
                uv = (uv & 0x80000000u) ? (uv & 0x7FFFFFFFu) : ~uv;
                watom[ln] = key / PW;
                wpos[ln]  = key % PW;
                wval[ln]  = __uint_as_float(uv);
            }
        }
        __syncthreads();

        // ---- commit recon (blocks 0-3, b = bk) ----
        if (bk < 4) {
            const float cv = wval[bk];
            const float* dw = dn + (long)watom[bk] * 512;
            recon[(long)(bk * C + (t >> 3)) * RC + wpos[bk] + (t & 7)] += cv * dw[t];
        }
        if (it == NITER - 1) break;

        // ---- write winner rows into wpad (data slots [8..15] of each 44-row) ----
        for (int i = t; i < 4 * 512; i += 512) {
            const int b = i >> 9, r = i & 511;
            wpad[b][(r >> 3) * WSTR + 8 + (r & 7)] = dn[(long)watom[b] * 512 + r];
        }
        __syncthreads();

        // ---- Gram: own (regs) x wpad -> g[a][bb][15] ----
        {
            float acc[15];
            #pragma unroll
            for (int i = 0; i < 15; ++i) acc[i] = 0.0f;
            #pragma unroll
            for (int j = 0; j < 8; ++j) {
                const float* wp = &wpad[bb_][(j * 8 + cg) * WSTR];
                float wr[24];
                *(float4*)(wr)      = *(const float4*)(wp);
                *(float4*)(wr + 4)  = *(const float4*)(wp + 4);
                *(float4*)(wr + 8)  = *(const float4*)(wp + 8);
                *(float4*)(wr + 12) = *(const float4*)(wp + 12);
                *(float4*)(wr + 16) = *(const float4*)(wp + 16);
                *(float4*)(wr + 20) = *(const float4*)(wp + 20);
                #pragma unroll
                for (int di = 0; di < 15; ++di)
                    #pragma unroll
                    for (int k = 0; k < 8; ++k)
                        acc[di] = fmaf(own[j][k], wr[15 + k - di], acc[di]);
            }
            #pragma unroll
            for (int di = 0; di < 15; ++di) {
                acc[di] += __shfl_xor(acc[di], 4);
                acc[di] += __shfl_xor(acc[di], 8);
                acc[di] += __shfl_xor(acc[di], 16);
            }
            if (cg == 0) {
                #pragma unroll
                for (int di = 0; di < 15; ++di) g[a_][bb_][di] = acc[di];
            }
        }
        __syncthreads();

        // ---- window update + winmax (8 threads per row) ----
        {
            const int q = wpos[r_b];
            const float val = wval[r_b];
            u64 wm = 0ull;
            #pragma unroll
            for (int h = 0; h < 2; ++h) {
                const int di = kk8 + h * 8;
                if (di < 15) {
                    const int p = q + 7 - di;
                    if (p >= 0 && p <= 256) {
                        const float nv = frow[p] - val * g[r_ai][r_b][di];
                        frow[p] = nv;
                        const u64 pm = packmax21(nv, rkey + p);
                        if (pm > wm) wm = pm;
                    }
                }
            }
            #pragma unroll
            for (int off = 1; off <= 4; off <<= 1) {
                u64 o = __shfl_xor(wm, off);
                if (o > wm) wm = o;
            }
            if (kk8 == 0) {
                const u64 old = rmax[r_b][r_ai];
                const unsigned okey = 0x1FFFFFu - (unsigned)((old >> 11) & 0x1FFFFFu);
                const int opos = (int)(okey % PW);
                if (opos >= q - 7 && opos <= q + 7) {
                    sflag[row] = 1;
                } else {
                    sflag[row] = 0;
                    rmax[r_b][r_ai] = (old > wm) ? old : wm;
                }
            }
        }
        __syncthreads();   // drains fm window stores (vmcnt) + sflag visibility

        // ---- conditional full row rescan ----
        if (sflag[row]) {
            u64 m = 0ull;
            #pragma unroll
            for (int i = 0; i <= 8; ++i) {
                const int idx4 = kk8 + i * 8;
                if (idx4 < 65) {
                    const float4 v = ((const float4*)frow)[idx4];
                    const unsigned e = rkey + idx4 * 4;
                    u64 q0 = packmax21(v.x, e);
                    u64 q1 = packmax21(v.y, e + 1);
                    u64 q2 = packmax21(v.z, e + 2);
                    u64 q3 = packmax21(v.w, e + 3);
                    if (q1 > q0) q0 = q1;
                    if (q3 > q2) q2 = q3;
                    if (q2 > q0) q0 = q2;
                    if (q0 > m)  m = q0;
                }
            }
            #pragma unroll
            for (int off = 1; off <= 4; off <<= 1) {
                u64 o = __shfl_xor(m, off);
                if (o > m) m = o;
            }
            if (kk8 == 0) rmax[r_b][r_ai] = m;
        }
        __syncthreads();

        // ---- publish next iteration's parts ----
        WINNER_STORE(pbuf ^ 1, it + 2);
    }
#undef WINNER_STORE
}

// ---------------- K7: copy recon[..., :T] to out ----------------
__global__ void k_out(const float* __restrict__ recon, float* __restrict__ out) {
    const int tid = blockIdx.x * blockDim.x + threadIdx.x;
    const int nth = gridDim.x * blockDim.x;
    for (int i = tid; i < B * C * (T / 4); i += nth) {
        const int bc = i >> 6;
        const int c4 = i & 63;
        ((float4*)out)[i] = *(const float4*)&recon[bc * RC + c4 * 4];
    }
}

extern "C" void kernel_launch(void* const* d_in, const int* in_sizes, int n_in,
                              void* d_out, int out_size, void* d_ws, size_t ws_size,
                              hipStream_t stream) {
    const float* x = (const float*)d_in[0];
    const float* d = (const float*)d_in[1];
    char* ws = (char*)d_ws;
    float* dn    = (float*)(ws + WS_DN);
    float* res   = (float*)(ws + WS_RES);
    float* recon = (float*)(ws + WS_RECON);
    float* fm    = (float*)(ws + WS_FM);
    u64*   parts = (u64*)(ws + WS_PART);
    float* out   = (float*)d_out;

    hipLaunchKernelGGL(k_norm, dim3(A / 4), dim3(256), 0, stream, d, dn);
    hipLaunchKernelGGL(k_init, dim3(1024), dim3(256), 0, stream, x, res, recon, fm, parts);
    hipLaunchKernelGGL(k_conv, dim3(A / 32, B), dim3(256), 0, stream, res, dn, fm);

    void* args[] = { (void*)&dn, (void*)&recon, (void*)&fm, (void*)&parts };
    hipLaunchCooperativeKernel((const void*)k_iter, dim3(NBLK), dim3(512), args, 0, stream);

    hipLaunchKernelGGL(k_out, dim3(64), dim3(256), 0, stream, recon, out);
}

// Round 7
// 853.610 us; speedup vs baseline: 1.1499x; 1.1499x over previous
//
#include <hip/hip_runtime.h>

#define B 4
#define C 64
#define T 256
#define A 4096
#define RC 264        // residual columns = T + 8
#define PW 260        // fm position stride (257 real, 3 sentinel)
#define NITER 32
#define NBLK 256      // k_iter blocks
#define ATB 16        // atoms owned per k_iter block
#define WSTR 44       // wpad channel stride (floats): cg*12 mod 32 all-distinct
#define WROW 2816     // 64*WSTR

// ---------------- workspace layout (bytes) ----------------
#define WS_DN     0            // A*512 f32            = 8,388,608
#define WS_RES    8388608      // B*C*RC f32           =   270,336
#define WS_RECON  8658944      // B*C*RC f32           =   270,336
#define WS_FM     8929280      // B*A*PW f32           = 17,039,360
#define WS_PART   25968640     // parts[4][256] u64 + win[4] u64 (contiguous)

typedef unsigned long long u64;

// pack: [monotone f32:32][~key:21][tag:11]; tag OR'd at store time
__device__ __forceinline__ u64 packmax21(float v, unsigned key) {
    unsigned u = __float_as_uint(v);
    u = (u & 0x80000000u) ? ~u : (u | 0x80000000u);
    return ((u64)u << 32) | ((u64)(0x1FFFFFu - key) << 11);
}

#define ALOAD(p)     __hip_atomic_load((p),  __ATOMIC_RELAXED, __HIP_MEMORY_SCOPE_AGENT)
#define ASTORE(p, v) __hip_atomic_store((p), (v), __ATOMIC_RELAXED, __HIP_MEMORY_SCOPE_AGENT)

// ---------------- K1: unit-norm the dictionary ----------------
__global__ void k_norm(const float* __restrict__ d, float* __restrict__ dn) {
    const int atom = blockIdx.x * 4 + (threadIdx.x >> 6);
    const int lane = threadIdx.x & 63;
    const float* src = d + atom * 512;
    float4 v0 = ((const float4*)src)[lane * 2];
    float4 v1 = ((const float4*)src)[lane * 2 + 1];
    float s = v0.x*v0.x + v0.y*v0.y + v0.z*v0.z + v0.w*v0.w
            + v1.x*v1.x + v1.y*v1.y + v1.z*v1.z + v1.w*v1.w;
    #pragma unroll
    for (int off = 32; off; off >>= 1) s += __shfl_xor(s, off);
    const float denom = sqrtf(s) + 1e-8f;
    float* dst = dn + atom * 512;
    float4 o0 = make_float4(v0.x/denom, v0.y/denom, v0.z/denom, v0.w/denom);
    float4 o1 = make_float4(v1.x/denom, v1.y/denom, v1.z/denom, v1.w/denom);
    ((float4*)dst)[lane * 2]     = o0;
    ((float4*)dst)[lane * 2 + 1] = o1;
}

// ---------------- K2: init res/recon/fm-edge + zero parts/win ----------------
__global__ void k_init(const float* __restrict__ x, float* __restrict__ res,
                       float* __restrict__ recon, float* __restrict__ fm,
                       u64* __restrict__ parts) {
    if (blockIdx.x == 0)
        for (int i = threadIdx.x; i < 1028; i += blockDim.x) parts[i] = 0ull;
    const int tid = blockIdx.x * blockDim.x + threadIdx.x;
    const int nth = gridDim.x * blockDim.x;
    for (int i = tid; i < B * C * RC; i += nth) {
        const int col = i % RC;
        const int bc  = i / RC;
        res[i]   = (col < T) ? x[bc * T + col] : 0.0f;
        recon[i] = 0.0f;
    }
    for (int i = tid; i < B * A; i += nth) {
        float* row = fm + (long)i * PW;
        row[256] = 0.0f;
        row[257] = -1e30f; row[258] = -1e30f; row[259] = -1e30f;
    }
}

// ---------------- K3: full correlation fm[b][a][p], p=0..255 ----------------
__global__ __launch_bounds__(256) void k_conv(const float* __restrict__ res,
                                              const float* __restrict__ dn,
                                              float* __restrict__ fm) {
    __shared__ __align__(16) float lr[16 * 264];
    __shared__ __align__(16) float ld[32 * 16 * 8];
    const int b  = blockIdx.y;
    const int a0 = blockIdx.x * 32;
    const int t  = threadIdx.x;
    const int slot = t >> 5;
    const int pg   = t & 31;
    const int p0   = pg * 8;

    float acc[4][8] = {};

    for (int cb = 0; cb < 4; ++cb) {
        const float* rsrc = res + b * C * RC + cb * 16 * RC;
        for (int i = t; i < 16 * 264; i += 256) lr[i] = rsrc[i];
        const float* dsrc = dn + (long)a0 * 512 + cb * 128;
        for (int i = t; i < 4096; i += 256)
            ld[i] = dsrc[(long)(i >> 7) * 512 + (i & 127)];
        __syncthreads();

        for (int cc = 0; cc < 16; ++cc) {
            float rv[16];
            const float* r = lr + cc * 264 + p0;
            *(float4*)(rv)      = *(const float4*)(r);
            *(float4*)(rv + 4)  = *(const float4*)(r + 4);
            *(float4*)(rv + 8)  = *(const float4*)(r + 8);
            *(float4*)(rv + 12) = *(const float4*)(r + 12);
            float dk[32];
            #pragma unroll
            for (int ai = 0; ai < 4; ++ai) {
                const float* dp = ld + ((slot * 4 + ai) * 16 + cc) * 8;
                *(float4*)(dk + ai * 8)     = *(const float4*)(dp);
                *(float4*)(dk + ai * 8 + 4) = *(const float4*)(dp + 4);
            }
            #pragma unroll
            for (int ai = 0; ai < 4; ++ai)
                #pragma unroll
                for (int pi = 0; pi < 8; ++pi)
                    #pragma unroll
                    for (int kk = 0; kk < 8; ++kk)
                        acc[ai][pi] = fmaf(rv[pi + kk], dk[ai * 8 + kk], acc[ai][pi]);
        }
        __syncthreads();
    }

    #pragma unroll
    for (int ai = 0; ai < 4; ++ai) {
        float* outp = fm + ((long)b * A + a0 + slot * 4 + ai) * PW + p0;
        *(float4*)(outp)     = *(const float4*)&acc[ai][0];
        *(float4*)(outp + 4) = *(const float4*)&acc[ai][4];
    }
}

// ---------------- K4: fused loop — hierarchical tagged sync ----------------
// parts[b][bk]: tagged u64 per block per b (single buffer; tag = iteration).
// Blocks 0-3 reduce their b-slice -> win[b] (one 32B line). Everyone polls win.
// Blocks 4-7 commit recon. Tags travel inside the atomic payload: no fences.
__global__ __launch_bounds__(512) void k_iter(const float* __restrict__ dn,
                                              float* __restrict__ recon,
                                              float* __restrict__ fm,
                                              u64* __restrict__ parts) {
    __shared__ __align__(16) float wpad[4][WROW];   // winner rows, stride-44 channels
    __shared__ float g[ATB][4][17];                 // Gram values (padded)
    __shared__ u64 rmax[4][ATB];                    // per-row packed maxima (tagless)
    __shared__ int sflag[64];
    __shared__ int   watom[4], wpos[4];
    __shared__ float wval[4];

    u64* win = parts + 1024;                        // win[4], one cache line

    const int bk = blockIdx.x;
    const int a0 = bk * ATB;
    const int t  = threadIdx.x;
    const int wv = t >> 6, ln = t & 63;
    const int a_ = t >> 5, tt = t & 31, bb_ = tt & 3, cg = tt >> 2;
    const int row = t >> 3, kk8 = t & 7;            // 64 rows x 8 threads
    const int r_ai = row & 15, r_b = row >> 4;
    float* frow = fm + ((long)r_b * A + a0 + r_ai) * PW;
    const unsigned rkey = (unsigned)((a0 + r_ai) * PW);

    // own atom channels in registers: channel c = j*8+cg of atom a0+a_
    float own[8][8];
    {
        const float* s = dn + (long)(a0 + a_) * 512 + cg * 8;
        #pragma unroll
        for (int j = 0; j < 8; ++j) {
            *(float4*)&own[j][0] = *(const float4*)(s + j * 64);
            *(float4*)&own[j][4] = *(const float4*)(s + j * 64 + 4);
        }
    }
    for (int i = t; i < 4 * WROW; i += 512) ((float*)wpad)[i] = 0.0f;

    // ---- initial full row scans -> rmax ----
    {
        u64 m = 0ull;
        #pragma unroll
        for (int i = 0; i <= 8; ++i) {
            const int idx4 = kk8 + i * 8;
            if (idx4 < 65) {
                const float4 v = ((const float4*)frow)[idx4];
                const unsigned e = rkey + idx4 * 4;
                u64 q0 = packmax21(v.x, e);
                u64 q1 = packmax21(v.y, e + 1);
                u64 q2 = packmax21(v.z, e + 2);
                u64 q3 = packmax21(v.w, e + 3);
                if (q1 > q0) q0 = q1;
                if (q3 > q2) q2 = q3;
                if (q2 > q0) q0 = q2;
                if (q0 > m)  m = q0;
            }
        }
        #pragma unroll
        for (int off = 1; off <= 4; off <<= 1) {
            u64 o = __shfl_xor(m, off);
            if (o > m) m = o;
        }
        if (kk8 == 0) rmax[r_b][r_ai] = m;
    }
    __syncthreads();

#define WINNER_STORE(tagv)                                                          \
    if (wv == 0) {                                                                  \
        const int b_ = ln >> 4, ai_ = ln & 15;                                      \
        u64 m = rmax[b_][ai_];                                                      \
        _Pragma("unroll")                                                           \
        for (int off = 1; off <= 8; off <<= 1) {                                    \
            u64 o = __shfl_xor(m, off);                                             \
            if (o > m) m = o;                                                       \
        }                                                                           \
        if (ai_ == 0) ASTORE(&parts[b_ * 256 + bk], m | (u64)(tagv));               \
    }

    WINNER_STORE(1);

    for (int it = 0; it < NITER; ++it) {
        const unsigned tagv = (unsigned)(it + 1);

        if (wv == 0) {
            // ---- reducers: blocks 0-3 reduce their b-slice -> win[b] ----
            if (bk < 4) {
                const u64* pb = parts + bk * 256 + ln * 4;
                u64 v0, v1, v2, v3;
                for (;;) {
                    v0 = ALOAD(pb + 0); v1 = ALOAD(pb + 1);
                    v2 = ALOAD(pb + 2); v3 = ALOAD(pb + 3);
                    bool ok = ((unsigned)(v0 & 0x7FFull) == tagv) &&
                              ((unsigned)(v1 & 0x7FFull) == tagv) &&
                              ((unsigned)(v2 & 0x7FFull) == tagv) &&
                              ((unsigned)(v3 & 0x7FFull) == tagv);
                    if (__all(ok)) break;
                    __builtin_amdgcn_s_sleep(1);
                }
                if (v1 > v0) v0 = v1;
                if (v3 > v2) v2 = v3;
                if (v2 > v0) v0 = v2;
                #pragma unroll
                for (int off = 1; off <= 32; off <<= 1) {
                    u64 o = __shfl_xor(v0, off);
                    if (o > v0) v0 = o;
                }
                if (ln == 0) ASTORE(&win[bk], v0);   // already tagged
            }
            // ---- everyone: poll the single win line ----
            u64 x = 0ull;
            for (;;) {
                if (ln < 4) x = ALOAD(&win[ln]);
                bool ok = (ln >= 4) || ((unsigned)(x & 0x7FFull) == tagv);
                if (__all(ok)) break;
                __builtin_amdgcn_s_sleep(1);
            }
            if (ln < 4) {
                const unsigned key = 0x1FFFFFu - (unsigned)((x >> 11) & 0x1FFFFFu);
                unsigned uv = (unsigned)(x >> 32);
                uv = (uv & 0x80000000u) ? (uv & 0x7FFFFFFFu) : ~uv;
                watom[ln] = key / PW;
                wpos[ln]  = key % PW;
                wval[ln]  = __uint_as_float(uv);
            }
        }
        __syncthreads();

        // ---- commit recon (blocks 4-7, b = bk-4) ----
        if (bk >= 4 && bk < 8) {
            const int b = bk - 4;
            const float cv = wval[b];
            const float* dw = dn + (long)watom[b] * 512;
            recon[(long)(b * C + (t >> 3)) * RC + wpos[b] + (t & 7)] += cv * dw[t];
        }
        if (it == NITER - 1) break;

        // ---- write winner rows into wpad (data slots [8..15] of each 44-row) ----
        for (int i = t; i < 4 * 512; i += 512) {
            const int b = i >> 9, r = i & 511;
            wpad[b][(r >> 3) * WSTR + 8 + (r & 7)] = dn[(long)watom[b] * 512 + r];
        }
        __syncthreads();

        // ---- Gram: own (regs) x wpad -> g[a][bb][15] ----
        {
            float acc[15];
            #pragma unroll
            for (int i = 0; i < 15; ++i) acc[i] = 0.0f;
            #pragma unroll
            for (int j = 0; j < 8; ++j) {
                const float* wp = &wpad[bb_][(j * 8 + cg) * WSTR];
                float wr[24];
                *(float4*)(wr)      = *(const float4*)(wp);
                *(float4*)(wr + 4)  = *(const float4*)(wp + 4);
                *(float4*)(wr + 8)  = *(const float4*)(wp + 8);
                *(float4*)(wr + 12) = *(const float4*)(wp + 12);
                *(float4*)(wr + 16) = *(const float4*)(wp + 16);
                *(float4*)(wr + 20) = *(const float4*)(wp + 20);
                #pragma unroll
                for (int di = 0; di < 15; ++di)
                    #pragma unroll
                    for (int k = 0; k < 8; ++k)
                        acc[di] = fmaf(own[j][k], wr[15 + k - di], acc[di]);
            }
            #pragma unroll
            for (int di = 0; di < 15; ++di) {
                acc[di] += __shfl_xor(acc[di], 4);
                acc[di] += __shfl_xor(acc[di], 8);
                acc[di] += __shfl_xor(acc[di], 16);
            }
            if (cg == 0) {
                #pragma unroll
                for (int di = 0; di < 15; ++di) g[a_][bb_][di] = acc[di];
            }
        }
        __syncthreads();

        // ---- window update + winmax (8 threads per row) ----
        {
            const int q = wpos[r_b];
            const float val = wval[r_b];
            u64 wm = 0ull;
            #pragma unroll
            for (int h = 0; h < 2; ++h) {
                const int di = kk8 + h * 8;
                if (di < 15) {
                    const int p = q + 7 - di;
                    if (p >= 0 && p <= 256) {
                        const float nv = frow[p] - val * g[r_ai][r_b][di];
                        frow[p] = nv;
                        const u64 pm = packmax21(nv, rkey + p);
                        if (pm > wm) wm = pm;
                    }
                }
            }
            #pragma unroll
            for (int off = 1; off <= 4; off <<= 1) {
                u64 o = __shfl_xor(wm, off);
                if (o > wm) wm = o;
            }
            if (kk8 == 0) {
                const u64 old = rmax[r_b][r_ai];
                const unsigned okey = 0x1FFFFFu - (unsigned)((old >> 11) & 0x1FFFFFu);
                const int opos = (int)(okey % PW);
                if (opos >= q - 7 && opos <= q + 7) {
                    sflag[row] = 1;
                } else {
                    sflag[row] = 0;
                    rmax[r_b][r_ai] = (old > wm) ? old : wm;
                }
            }
        }
        __syncthreads();

        // ---- conditional full row rescan ----
        if (sflag[row]) {
            u64 m = 0ull;
            #pragma unroll
            for (int i = 0; i <= 8; ++i) {
                const int idx4 = kk8 + i * 8;
                if (idx4 < 65) {
                    const float4 v = ((const float4*)frow)[idx4];
                    const unsigned e = rkey + idx4 * 4;
                    u64 q0 = packmax21(v.x, e);
                    u64 q1 = packmax21(v.y, e + 1);
                    u64 q2 = packmax21(v.z, e + 2);
                    u64 q3 = packmax21(v.w, e + 3);
                    if (q1 > q0) q0 = q1;
                    if (q3 > q2) q2 = q3;
                    if (q2 > q0) q0 = q2;
                    if (q0 > m)  m = q0;
                }
            }
            #pragma unroll
            for (int off = 1; off <= 4; off <<= 1) {
                u64 o = __shfl_xor(m, off);
                if (o > m) m = o;
            }
            if (kk8 == 0) rmax[r_b][r_ai] = m;
        }
        __syncthreads();

        // ---- publish next iteration's parts ----
        WINNER_STORE(it + 2);
    }
#undef WINNER_STORE
}

// ---------------- K7: copy recon[..., :T] to out ----------------
__global__ void k_out(const float* __restrict__ recon, float* __restrict__ out) {
    const int tid = blockIdx.x * blockDim.x + threadIdx.x;
    const int nth = gridDim.x * blockDim.x;
    for (int i = tid; i < B * C * (T / 4); i += nth) {
        const int bc = i >> 6;
        const int c4 = i & 63;
        ((float4*)out)[i] = *(const float4*)&recon[bc * RC + c4 * 4];
    }
}

extern "C" void kernel_launch(void* const* d_in, const int* in_sizes, int n_in,
                              void* d_out, int out_size, void* d_ws, size_t ws_size,
                              hipStream_t stream) {
    const float* x = (const float*)d_in[0];
    const float* d = (const float*)d_in[1];
    char* ws = (char*)d_ws;
    float* dn    = (float*)(ws + WS_DN);
    float* res   = (float*)(ws + WS_RES);
    float* recon = (float*)(ws + WS_RECON);
    float* fm    = (float*)(ws + WS_FM);
    u64*   parts = (u64*)(ws + WS_PART);
    float* out   = (float*)d_out;

    hipLaunchKernelGGL(k_norm, dim3(A / 4), dim3(256), 0, stream, d, dn);
    hipLaunchKernelGGL(k_init, dim3(1024), dim3(256), 0, stream, x, res, recon, fm, parts);
    hipLaunchKernelGGL(k_conv, dim3(A / 32, B), dim3(256), 0, stream, res, dn, fm);

    void* args[] = { (void*)&dn, (void*)&recon, (void*)&fm, (void*)&parts };
    hipLaunchCooperativeKernel((const void*)k_iter, dim3(NBLK), dim3(512), args, 0, stream);

    hipLaunchKernelGGL(k_out, dim3(64), dim3(256), 0, stream, recon, out);
}